// Round 1
// baseline (1382.051 us; speedup 1.0000x reference)
//
#include <hip/hip_runtime.h>
#include <cmath>

constexpr int B_ = 4, H_ = 8, TQ_ = 128, TK_ = 128, DH_ = 64;
constexpr int NMEM = 100000, DM = 512, TOPK = 32, HID = 128;
constexpr int R_ = B_ * TQ_;                    // 512 memory rows (b,t)
constexpr int CTILE = 128, RTILE = 64;
constexpr int NCH = (NMEM + CTILE - 1) / CTILE; // 782
constexpr int KC = 8;                           // candidates kept per chunk
constexpr int NCAND = NCH * KC;                 // 6256
constexpr int KSEL = 40;                        // rescored candidates

// ---------------------------------------------------------------- k1: scores GEMM + per-chunk top-8
__global__ __launch_bounds__(256)
void k1_scores_topk(const float* __restrict__ qm, const float* __restrict__ mk,
                    float* __restrict__ cand_s, int* __restrict__ cand_i)
{
    const int rt = blockIdx.x;      // 0..7 row tile
    const int chunk = blockIdx.y;   // 0..781
    const int row0 = rt * RTILE;
    const int col0 = chunk * CTILE;
    const int tid = threadIdx.x;
    const int tx = tid & 15;        // col group (8 cols)
    const int ty = tid >> 4;        // row group (4 rows)

    __shared__ float qs[RTILE][36];
    __shared__ float ks[32][132];
    __shared__ float sc[RTILE][CTILE + 1];

    float acc[4][8];
#pragma unroll
    for (int i = 0; i < 4; ++i)
#pragma unroll
        for (int j = 0; j < 8; ++j) acc[i][j] = 0.f;

    for (int d0 = 0; d0 < DM; d0 += 32) {
        // stage q slab: 64 rows x 32 dims = 512 float4
#pragma unroll
        for (int l = 0; l < 2; ++l) {
            int f = tid + l * 256;
            int r = f >> 3, c4 = f & 7;
            float4 v = *reinterpret_cast<const float4*>(qm + (size_t)(row0 + r) * DM + d0 + c4 * 4);
            *reinterpret_cast<float4*>(&qs[r][c4 * 4]) = v;
        }
        // stage keys slab transposed: 128 cols x 32 dims
#pragma unroll
        for (int l = 0; l < 4; ++l) {
            int f = tid + l * 256;
            int c = f >> 3, k4 = f & 7;
            int col = col0 + c;
            float4 v = make_float4(0.f, 0.f, 0.f, 0.f);
            if (col < NMEM)
                v = *reinterpret_cast<const float4*>(mk + (size_t)col * DM + d0 + k4 * 4);
            ks[k4 * 4 + 0][c] = v.x;
            ks[k4 * 4 + 1][c] = v.y;
            ks[k4 * 4 + 2][c] = v.z;
            ks[k4 * 4 + 3][c] = v.w;
        }
        __syncthreads();
#pragma unroll
        for (int kk = 0; kk < 32; ++kk) {
            float a0 = qs[ty * 4 + 0][kk];
            float a1 = qs[ty * 4 + 1][kk];
            float a2 = qs[ty * 4 + 2][kk];
            float a3 = qs[ty * 4 + 3][kk];
            float4 b0 = *reinterpret_cast<const float4*>(&ks[kk][tx * 8]);
            float4 b1v = *reinterpret_cast<const float4*>(&ks[kk][tx * 8 + 4]);
            float bb[8] = {b0.x, b0.y, b0.z, b0.w, b1v.x, b1v.y, b1v.z, b1v.w};
#pragma unroll
            for (int j = 0; j < 8; ++j) {
                acc[0][j] = fmaf(a0, bb[j], acc[0][j]);
                acc[1][j] = fmaf(a1, bb[j], acc[1][j]);
                acc[2][j] = fmaf(a2, bb[j], acc[2][j]);
                acc[3][j] = fmaf(a3, bb[j], acc[3][j]);
            }
        }
        __syncthreads();
    }
    // scores to LDS with OOB mask
#pragma unroll
    for (int i = 0; i < 4; ++i)
#pragma unroll
        for (int j = 0; j < 8; ++j) {
            int c = tx * 8 + j;
            sc[ty * 4 + i][c] = (col0 + c < NMEM) ? acc[i][j] : -INFINITY;
        }
    __syncthreads();
    // per-row top-8, 4 threads per row (intra-wave quad)
    const int rid = tid >> 2, sub = tid & 3;
    float* srow = sc[rid];
    size_t base = (size_t)(row0 + rid) * NCAND + (size_t)chunk * KC;
    for (int it = 0; it < KC; ++it) {
        float best = -INFINITY; int bi = 0;
        for (int c = sub; c < CTILE; c += 4) {
            float v = srow[c];
            if (v > best) { best = v; bi = c; }
        }
#pragma unroll
        for (int off = 1; off < 4; off <<= 1) {
            float ob = __shfl_xor(best, off);
            int   oi = __shfl_xor(bi, off);
            if (ob > best || (ob == best && oi < bi)) { best = ob; bi = oi; }
        }
        if (sub == 0) { cand_s[base + it] = best; cand_i[base + it] = col0 + bi; }
        srow[bi] = -INFINITY;   // all 4 lanes agree on bi
    }
}

// ---------------------------------------------------------------- k2: merge candidates, fp64 rescore, exact top-32
__global__ __launch_bounds__(256)
void k2_select(const float* __restrict__ qm, const float* __restrict__ mk,
               const float* __restrict__ cand_s, const int* __restrict__ cand_i,
               int* __restrict__ sel)
{
    const int row = blockIdx.x;
    const int tid = threadIdx.x;
    const int lane = tid & 63, wv = tid >> 6;
    __shared__ float ls[NCAND];
    __shared__ int   li[NCAND];
    __shared__ float rs[4]; __shared__ int rp[4];
    __shared__ int    sidx[KSEL];
    __shared__ double rsc[KSEL];

    const float* cs = cand_s + (size_t)row * NCAND;
    const int*   ci = cand_i + (size_t)row * NCAND;
    for (int i = tid; i < NCAND; i += 256) { ls[i] = cs[i]; li[i] = ci[i]; }
    __syncthreads();

    // approx top-KSEL by fp32 candidate score
    for (int it = 0; it < KSEL; ++it) {
        float best = -INFINITY; int bp = 0;
        for (int i = tid; i < NCAND; i += 256) {
            float v = ls[i];
            if (v > best) { best = v; bp = i; }
        }
#pragma unroll
        for (int off = 1; off < 64; off <<= 1) {
            float ob = __shfl_xor(best, off);
            int   op = __shfl_xor(bp, off);
            if (ob > best || (ob == best && op < bp)) { best = ob; bp = op; }
        }
        if (lane == 0) { rs[wv] = best; rp[wv] = bp; }
        __syncthreads();
        if (tid == 0) {
            float bb = rs[0]; int pp = rp[0];
            for (int w = 1; w < 4; ++w)
                if (rs[w] > bb || (rs[w] == bb && rp[w] < pp)) { bb = rs[w]; pp = rp[w]; }
            sidx[it] = li[pp];
            ls[pp] = -INFINITY;
        }
        __syncthreads();
    }

    // fp64 rescore: wave wv handles candidate c0+wv
    const float* qrow = qm + (size_t)row * DM;
    for (int c0 = 0; c0 < KSEL; c0 += 4) {
        int c = c0 + wv;
        const float* krow = mk + (size_t)sidx[c] * DM;
        double p = 0.0;
        for (int d = lane; d < DM; d += 64)
            p += (double)qrow[d] * (double)krow[d];
#pragma unroll
        for (int off = 1; off < 64; off <<= 1)
            p += __shfl_xor(p, off);
        if (lane == 0) rsc[c] = p;
    }
    __syncthreads();
    // exact ordered top-32 (desc score, tie -> lower index)
    if (tid == 0) {
        unsigned long long used = 0ull;
        for (int s = 0; s < TOPK; ++s) {
            double best = -1.0e300; int bc = 0; int bmi = 0x7fffffff;
            for (int c = 0; c < KSEL; ++c) {
                if (used & (1ull << c)) continue;
                double v = rsc[c]; int mi = sidx[c];
                if (v > best || (v == best && mi < bmi)) { best = v; bc = c; bmi = mi; }
            }
            used |= (1ull << bc);
            sel[row * TOPK + s] = bmi;
        }
    }
}

// ---------------------------------------------------------------- k3: gather + Wk/Wv projection
__global__ __launch_bounds__(64)
void k3_proj(const float* __restrict__ mk, const float* __restrict__ mv,
             const float* __restrict__ Wk, const float* __restrict__ Wv,
             const int* __restrict__ sel,
             float* __restrict__ Kmem, float* __restrict__ Vmem)
{
    const int i0 = blockIdx.x * 8;   // pair base, pair = row*TOPK+k (16384 total)
    const int tid = threadIdx.x;     // 64
    __shared__ float s[2][8][DM];    // [mat][row][d] 32 KiB
    __shared__ int si[8];
    if (tid < 8) si[tid] = sel[i0 + tid];
    __syncthreads();
    for (int l = tid; l < 1024; l += 64) {   // 8 rows x 128 float4 per matrix
        int r = l >> 7, c4 = l & 127;
        *reinterpret_cast<float4*>(&s[0][r][c4 * 4]) =
            *reinterpret_cast<const float4*>(mk + (size_t)si[r] * DM + c4 * 4);
        *reinterpret_cast<float4*>(&s[1][r][c4 * 4]) =
            *reinterpret_cast<const float4*>(mv + (size_t)si[r] * DM + c4 * 4);
    }
    __syncthreads();
    const int doV = tid >> 5;        // 0: K path, 1: V path
    const int ep = tid & 31;         // handles e=ep and e=ep+32
    const float* W = doV ? Wv : Wk;
    const float* w0 = W + (size_t)ep * DM;
    const float* w1 = W + (size_t)(ep + 32) * DM;
    float a0[8], a1[8];
#pragma unroll
    for (int r = 0; r < 8; ++r) { a0[r] = 0.f; a1[r] = 0.f; }
    for (int d4 = 0; d4 < DM / 4; ++d4) {
        float4 x0 = *reinterpret_cast<const float4*>(w0 + d4 * 4);
        float4 x1 = *reinterpret_cast<const float4*>(w1 + d4 * 4);
#pragma unroll
        for (int r = 0; r < 8; ++r) {
            float4 m = *reinterpret_cast<const float4*>(&s[doV][r][d4 * 4]);
            a0[r] = fmaf(x0.x, m.x, fmaf(x0.y, m.y, fmaf(x0.z, m.z, fmaf(x0.w, m.w, a0[r]))));
            a1[r] = fmaf(x1.x, m.x, fmaf(x1.y, m.y, fmaf(x1.z, m.z, fmaf(x1.w, m.w, a1[r]))));
        }
    }
    float* O = doV ? Vmem : Kmem;
#pragma unroll
    for (int r = 0; r < 8; ++r) {
        O[(size_t)(i0 + r) * DH_ + ep] = a0[r];
        O[(size_t)(i0 + r) * DH_ + ep + 32] = a1[r];
    }
}

// ---------------------------------------------------------------- k4: W1 partial projections
__global__ __launch_bounds__(128)
void k4_parts(const float* __restrict__ q, const float* __restrict__ kctx,
              const float* __restrict__ Kmem, const float* __restrict__ W1,
              float* __restrict__ qp, float* __restrict__ kcp, float* __restrict__ kmp)
{
    const int bid = blockIdx.x;
    const int tid = threadIdx.x;  // 128 = e
    const float* src; float* dst; int woff;
    if (bid < 1024)      { int r0 = bid * 4;          src = q    + (size_t)r0 * DH_; dst = qp  + (size_t)r0 * HID; woff = 0; }
    else if (bid < 2048) { int r0 = (bid - 1024) * 4; src = kctx + (size_t)r0 * DH_; dst = kcp + (size_t)r0 * HID; woff = DH_; }
    else                 { int r0 = (bid - 2048) * 4; src = Kmem + (size_t)r0 * DH_; dst = kmp + (size_t)r0 * HID; woff = DH_; }
    __shared__ float s[4][DH_];
    for (int l = tid; l < 4 * DH_; l += 128) s[l >> 6][l & 63] = src[l];
    __syncthreads();
    const float* wr = W1 + (size_t)tid * (2 * DH_) + woff;
    float a0 = 0.f, a1 = 0.f, a2 = 0.f, a3 = 0.f;
#pragma unroll 8
    for (int d = 0; d < DH_; ++d) {
        float w = wr[d];
        a0 = fmaf(s[0][d], w, a0);
        a1 = fmaf(s[1][d], w, a1);
        a2 = fmaf(s[2][d], w, a2);
        a3 = fmaf(s[3][d], w, a3);
    }
    dst[0 * HID + tid] = a0;
    dst[1 * HID + tid] = a1;
    dst[2 * HID + tid] = a2;
    dst[3 * HID + tid] = a3;
}

// ---------------------------------------------------------------- k5: MLP scores + softmax + weighted sum
__global__ __launch_bounds__(256)
void k5_attn(const float* __restrict__ qp, const float* __restrict__ kcp,
             const float* __restrict__ kmp, const float* __restrict__ vctx,
             const float* __restrict__ Vmem, const float* __restrict__ b1,
             const float* __restrict__ w2, const float* __restrict__ b2,
             float* __restrict__ out, float* __restrict__ outw)
{
    const int bid = blockIdx.x;
    const int t = bid & 127, h = (bid >> 7) & 7, b = bid >> 10;
    const int tid = threadIdx.x;
    const int lane = tid & 63, wv = tid >> 6;
    const int bh = b * H_ + h, bht = bh * TQ_ + t, bt = b * TQ_ + t;
    constexpr int NS = TK_ + TOPK;  // 160
    __shared__ float qps[HID], b1s[HID], w2s[HID];
    __shared__ float sc[NS];
    __shared__ float red[8];
    if (tid < HID) {
        qps[tid] = qp[(size_t)bht * HID + tid];
        b1s[tid] = b1[tid];
        w2s[tid] = w2[tid];
    }
    __syncthreads();
    const float bias2 = b2[0];
    if (tid < NS) {
        const float* kr = (tid < TK_) ? (kcp + ((size_t)bh * TK_ + tid) * HID)
                                      : (kmp + ((size_t)bt * TOPK + (tid - TK_)) * HID);
        float acc = 0.f;
#pragma unroll 4
        for (int e4 = 0; e4 < HID / 4; ++e4) {
            float4 kv = *reinterpret_cast<const float4*>(kr + e4 * 4);
            acc += fmaxf(qps[e4 * 4 + 0] + kv.x + b1s[e4 * 4 + 0], 0.f) * w2s[e4 * 4 + 0];
            acc += fmaxf(qps[e4 * 4 + 1] + kv.y + b1s[e4 * 4 + 1], 0.f) * w2s[e4 * 4 + 1];
            acc += fmaxf(qps[e4 * 4 + 2] + kv.z + b1s[e4 * 4 + 2], 0.f) * w2s[e4 * 4 + 2];
            acc += fmaxf(qps[e4 * 4 + 3] + kv.w + b1s[e4 * 4 + 3], 0.f) * w2s[e4 * 4 + 3];
        }
        sc[tid] = acc + bias2;
    }
    __syncthreads();
    float v = (tid < NS) ? sc[tid] : -INFINITY;
    float m = v;
#pragma unroll
    for (int off = 1; off < 64; off <<= 1) m = fmaxf(m, __shfl_xor(m, off));
    if (lane == 0) red[wv] = m;
    __syncthreads();
    if (tid == 0) red[4] = fmaxf(fmaxf(red[0], red[1]), fmaxf(red[2], red[3]));
    __syncthreads();
    const float mm = red[4];
    float e = (tid < NS) ? expf(v - mm) : 0.f;
    float ssum = e;
#pragma unroll
    for (int off = 1; off < 64; off <<= 1) ssum += __shfl_xor(ssum, off);
    if (lane == 0) red[wv] = ssum;
    __syncthreads();
    if (tid == 0) red[5] = red[0] + red[1] + red[2] + red[3];
    __syncthreads();
    const float inv = 1.f / red[5];
    if (tid < NS) {
        float w = e * inv;
        sc[tid] = w;
        outw[(size_t)bht * NS + tid] = w;
    }
    __syncthreads();
    if (tid < DH_) {
        float acc = 0.f;
        const float* vb = vctx + (size_t)bh * TK_ * DH_ + tid;
        for (int s2 = 0; s2 < TK_; ++s2) acc = fmaf(sc[s2], vb[(size_t)s2 * DH_], acc);
        const float* vm = Vmem + (size_t)bt * TOPK * DH_ + tid;
#pragma unroll
        for (int kk = 0; kk < TOPK; ++kk) acc = fmaf(sc[TK_ + kk], vm[(size_t)kk * DH_], acc);
        out[(size_t)bht * DH_ + tid] = acc;
    }
}

// ---------------------------------------------------------------- launch
extern "C" void kernel_launch(void* const* d_in, const int* in_sizes, int n_in,
                              void* d_out, int out_size, void* d_ws, size_t ws_size,
                              hipStream_t stream)
{
    const float* q    = (const float*)d_in[0];
    const float* kctx = (const float*)d_in[1];
    const float* vctx = (const float*)d_in[2];
    const float* qm   = (const float*)d_in[3];
    const float* mk   = (const float*)d_in[4];
    const float* mv   = (const float*)d_in[5];
    const float* Wk   = (const float*)d_in[6];
    const float* Wv   = (const float*)d_in[7];
    const float* W1   = (const float*)d_in[8];
    const float* b1   = (const float*)d_in[9];
    const float* w2   = (const float*)d_in[10];
    const float* b2   = (const float*)d_in[11];
    float* out  = (float*)d_out;
    float* outw = out + (size_t)B_ * H_ * TQ_ * DH_;

    char* w = (char*)d_ws;
    float* cand_s = (float*)w; w += sizeof(float) * R_ * NCAND;
    int*   cand_i = (int*)w;   w += sizeof(int) * R_ * NCAND;
    int*   sel    = (int*)w;   w += sizeof(int) * R_ * TOPK;
    float* Kmem   = (float*)w; w += sizeof(float) * R_ * TOPK * DH_;
    float* Vmem   = (float*)w; w += sizeof(float) * R_ * TOPK * DH_;
    float* qp     = (float*)w; w += sizeof(float) * B_ * H_ * TQ_ * HID;
    float* kcp    = (float*)w; w += sizeof(float) * B_ * H_ * TK_ * HID;
    float* kmp    = (float*)w; w += sizeof(float) * R_ * TOPK * HID;

    hipLaunchKernelGGL(k1_scores_topk, dim3(8, NCH), dim3(256), 0, stream, qm, mk, cand_s, cand_i);
    hipLaunchKernelGGL(k2_select, dim3(R_), dim3(256), 0, stream, qm, mk, cand_s, cand_i, sel);
    hipLaunchKernelGGL(k3_proj, dim3(R_ * TOPK / 8), dim3(64), 0, stream, mk, mv, Wk, Wv, sel, Kmem, Vmem);
    hipLaunchKernelGGL(k4_parts, dim3(6144), dim3(128), 0, stream, q, kctx, Kmem, W1, qp, kcp, kmp);
    hipLaunchKernelGGL(k5_attn, dim3(B_ * H_ * TQ_), dim3(256), 0, stream, qp, kcp, kmp, vctx, Vmem, b1, w2, b2, out, outw);
}

// Round 2
// 612.821 us; speedup vs baseline: 2.2552x; 2.2552x over previous
//
#include <hip/hip_runtime.h>
#include <cmath>

constexpr int B_ = 4, H_ = 8, TQ_ = 128, TK_ = 128, DH_ = 64;
constexpr int NMEM = 100000, DM = 512, TOPK = 32, HID = 128;
constexpr int R_ = B_ * TQ_;                    // 512 memory rows (b,t)
constexpr int CTILE = 128, RTILE = 64;
constexpr int NCH = (NMEM + CTILE - 1) / CTILE; // 782
constexpr int NPAD = NCH * CTILE;               // 100096 padded rows
constexpr int KC = 8;                           // candidates kept per chunk
constexpr int NCAND = NCH * KC;                 // 6256
constexpr int KSEL = 48;                        // rescored candidates

using f32x4  = __attribute__((ext_vector_type(4))) float;
using bf16x8 = __attribute__((ext_vector_type(8))) short;
using u16x8  = __attribute__((ext_vector_type(8))) unsigned short;

#define GLOAD16(g, l) __builtin_amdgcn_global_load_lds( \
    (const __attribute__((address_space(1))) void*)(g), \
    (__attribute__((address_space(3))) void*)(l), 16, 0, 0)

static __device__ __forceinline__ unsigned short f2bf(float f) {
    unsigned u = __float_as_uint(f);
    u = (u + 0x7FFFu + ((u >> 16) & 1u)) >> 16;
    return (unsigned short)u;
}

// ---------------------------------------------------------------- k0: fp32 -> bf16 convert (pad rows zeroed)
__global__ __launch_bounds__(256)
void k0_cvt(const float* __restrict__ src, unsigned short* __restrict__ dst,
            long n, long ntot)
{
    long stride = (long)gridDim.x * 256 * 8;
    for (long base = ((long)blockIdx.x * 256 + threadIdx.x) * 8; base < ntot; base += stride) {
        u16x8 o;
        if (base < n) {
            float4 v0 = *reinterpret_cast<const float4*>(src + base);
            float4 v1 = *reinterpret_cast<const float4*>(src + base + 4);
            o[0] = f2bf(v0.x); o[1] = f2bf(v0.y); o[2] = f2bf(v0.z); o[3] = f2bf(v0.w);
            o[4] = f2bf(v1.x); o[5] = f2bf(v1.y); o[6] = f2bf(v1.z); o[7] = f2bf(v1.w);
        } else {
            o = (u16x8)0;
        }
        *reinterpret_cast<u16x8*>(dst + base) = o;
    }
}

// ---------------------------------------------------------------- k1: bf16 MFMA scores + per-chunk top-8
__global__ __launch_bounds__(256)
void k1_mfma(const unsigned short* __restrict__ qmb, const unsigned short* __restrict__ mkb,
             float* __restrict__ cand_s, int* __restrict__ cand_i)
{
    const int rt = blockIdx.x;      // 0..7 row tile (64 rows)
    const int chunk = blockIdx.y;   // 0..781 (128 cols)
    const int row0 = rt * RTILE;
    const int col0 = chunk * CTILE;
    const int tid = threadIdx.x;
    const int lane = tid & 63, w = tid >> 6;
    const int wm = w >> 1, wn = w & 1;          // wave computes 32x64

    // union: tiles A[64][64]bf16 @0 (8 KiB) + B[128][64]bf16 @8192 (16 KiB)  |  sc[64][129] f32 (33024 B)
    __shared__ __align__(16) char smem[64 * 129 * 4];
    char* Abase = smem;
    char* Bbase = smem + 8192;
    float* scf = (float*)smem;

    f32x4 acc[2][4];
#pragma unroll
    for (int mi = 0; mi < 2; ++mi)
#pragma unroll
        for (int ni = 0; ni < 4; ++ni) acc[mi][ni] = (f32x4)0.f;

    for (int ks = 0; ks < 8; ++ks) {
        const int kb = ks * 128;    // byte offset of K-slice within a 1024-B row
        // stage A: 64 rows x 128 B (linear dest, inverse-swizzled source)
#pragma unroll
        for (int p = 0; p < 2; ++p) {
            int X = p * 4096 + w * 1024 + lane * 16;
            int r = X >> 7, c = (X & 127) ^ ((r & 7) << 4);
            const char* src = (const char*)qmb + (size_t)(row0 + r) * 1024 + kb + c;
            GLOAD16(src, Abase + p * 4096 + w * 1024);
        }
        // stage B: 128 rows x 128 B
#pragma unroll
        for (int p = 0; p < 4; ++p) {
            int X = p * 4096 + w * 1024 + lane * 16;
            int r = X >> 7, c = (X & 127) ^ ((r & 7) << 4);
            const char* src = (const char*)mkb + (size_t)(col0 + r) * 1024 + kb + c;
            GLOAD16(src, Bbase + p * 4096 + w * 1024);
        }
        __syncthreads();
#pragma unroll
        for (int kk = 0; kk < 2; ++kk) {
            bf16x8 af[2], bfr[4];
#pragma unroll
            for (int mi = 0; mi < 2; ++mi) {
                int rr = wm * 32 + mi * 16 + (lane & 15);
                int L = rr * 128 + kk * 64 + ((lane >> 4) * 16);
                af[mi] = *reinterpret_cast<const bf16x8*>(Abase + (L ^ ((rr & 7) << 4)));
            }
#pragma unroll
            for (int ni = 0; ni < 4; ++ni) {
                int rr = wn * 64 + ni * 16 + (lane & 15);
                int L = rr * 128 + kk * 64 + ((lane >> 4) * 16);
                bfr[ni] = *reinterpret_cast<const bf16x8*>(Bbase + (L ^ ((rr & 7) << 4)));
            }
#pragma unroll
            for (int mi = 0; mi < 2; ++mi)
#pragma unroll
                for (int ni = 0; ni < 4; ++ni)
                    acc[mi][ni] = __builtin_amdgcn_mfma_f32_16x16x32_bf16(af[mi], bfr[ni], acc[mi][ni], 0, 0, 0);
        }
        __syncthreads();
    }

    // scores -> LDS (C/D layout: col=lane&15, row=(lane>>4)*4+reg), OOB cols masked
#pragma unroll
    for (int mi = 0; mi < 2; ++mi)
#pragma unroll
        for (int ni = 0; ni < 4; ++ni)
#pragma unroll
            for (int reg = 0; reg < 4; ++reg) {
                int rr = wm * 32 + mi * 16 + (lane >> 4) * 4 + reg;
                int cc = wn * 64 + ni * 16 + (lane & 15);
                scf[rr * 129 + cc] = (col0 + cc < NMEM) ? acc[mi][ni][reg] : -INFINITY;
            }
    __syncthreads();

    // per-row top-8, 4 threads per row (intra-wave quad)
    const int rid = tid >> 2, sub = tid & 3;
    float* srow = scf + rid * 129;
    size_t base = (size_t)(row0 + rid) * NCAND + (size_t)chunk * KC;
    for (int it = 0; it < KC; ++it) {
        float best = -INFINITY; int bi = 0;
        for (int c = sub; c < CTILE; c += 4) {
            float v = srow[c];
            if (v > best) { best = v; bi = c; }
        }
#pragma unroll
        for (int off = 1; off < 4; off <<= 1) {
            float ob = __shfl_xor(best, off);
            int   oi = __shfl_xor(bi, off);
            if (ob > best || (ob == best && oi < bi)) { best = ob; bi = oi; }
        }
        if (sub == 0) { cand_s[base + it] = best; cand_i[base + it] = col0 + bi; }
        srow[bi] = -INFINITY;   // all 4 lanes agree on bi
    }
}

// ---------------------------------------------------------------- k2: merge candidates, fp64 rescore, exact top-32
__global__ __launch_bounds__(256)
void k2_select(const float* __restrict__ qm, const float* __restrict__ mk,
               const float* __restrict__ cand_s, const int* __restrict__ cand_i,
               int* __restrict__ sel)
{
    const int row = blockIdx.x;
    const int tid = threadIdx.x;
    const int lane = tid & 63, wv = tid >> 6;
    __shared__ float ls[NCAND];
    __shared__ int   li[NCAND];
    __shared__ float rs[4]; __shared__ int rp[4];
    __shared__ int    sidx[KSEL];
    __shared__ double rsc[KSEL];

    const float* cs = cand_s + (size_t)row * NCAND;
    const int*   ci = cand_i + (size_t)row * NCAND;
    for (int i = tid; i < NCAND; i += 256) { ls[i] = cs[i]; li[i] = ci[i]; }
    __syncthreads();

    // approx top-KSEL by bf16-derived candidate score
    for (int it = 0; it < KSEL; ++it) {
        float best = -INFINITY; int bp = 0;
        for (int i = tid; i < NCAND; i += 256) {
            float v = ls[i];
            if (v > best) { best = v; bp = i; }
        }
#pragma unroll
        for (int off = 1; off < 64; off <<= 1) {
            float ob = __shfl_xor(best, off);
            int   op = __shfl_xor(bp, off);
            if (ob > best || (ob == best && op < bp)) { best = ob; bp = op; }
        }
        if (lane == 0) { rs[wv] = best; rp[wv] = bp; }
        __syncthreads();
        if (tid == 0) {
            float bb = rs[0]; int pp = rp[0];
            for (int w = 1; w < 4; ++w)
                if (rs[w] > bb || (rs[w] == bb && rp[w] < pp)) { bb = rs[w]; pp = rp[w]; }
            sidx[it] = li[pp];
            ls[pp] = -INFINITY;
        }
        __syncthreads();
    }

    // fp64 rescore from ORIGINAL fp32 data: wave wv handles candidate c0+wv
    const float* qrow = qm + (size_t)row * DM;
    for (int c0 = 0; c0 < KSEL; c0 += 4) {
        int c = c0 + wv;
        const float* krow = mk + (size_t)sidx[c] * DM;
        double p = 0.0;
        for (int d = lane; d < DM; d += 64)
            p += (double)qrow[d] * (double)krow[d];
#pragma unroll
        for (int off = 1; off < 64; off <<= 1)
            p += __shfl_xor(p, off);
        if (lane == 0) rsc[c] = p;
    }
    __syncthreads();
    // exact ordered top-32 (desc score, tie -> lower index)
    if (tid == 0) {
        unsigned long long used = 0ull;
        for (int s = 0; s < TOPK; ++s) {
            double best = -1.0e300; int bc = 0; int bmi = 0x7fffffff;
            for (int c = 0; c < KSEL; ++c) {
                if (used & (1ull << c)) continue;
                double v = rsc[c]; int mi = sidx[c];
                if (v > best || (v == best && mi < bmi)) { best = v; bc = c; bmi = mi; }
            }
            used |= (1ull << bc);
            sel[row * TOPK + s] = bmi;
        }
    }
}

// ---------------------------------------------------------------- k3: gather + Wk/Wv projection
__global__ __launch_bounds__(64)
void k3_proj(const float* __restrict__ mk, const float* __restrict__ mv,
             const float* __restrict__ Wk, const float* __restrict__ Wv,
             const int* __restrict__ sel,
             float* __restrict__ Kmem, float* __restrict__ Vmem)
{
    const int i0 = blockIdx.x * 8;   // pair base, pair = row*TOPK+k (16384 total)
    const int tid = threadIdx.x;     // 64
    __shared__ float s[2][8][DM];    // [mat][row][d] 32 KiB
    __shared__ int si[8];
    if (tid < 8) si[tid] = sel[i0 + tid];
    __syncthreads();
    for (int l = tid; l < 1024; l += 64) {   // 8 rows x 128 float4 per matrix
        int r = l >> 7, c4 = l & 127;
        *reinterpret_cast<float4*>(&s[0][r][c4 * 4]) =
            *reinterpret_cast<const float4*>(mk + (size_t)si[r] * DM + c4 * 4);
        *reinterpret_cast<float4*>(&s[1][r][c4 * 4]) =
            *reinterpret_cast<const float4*>(mv + (size_t)si[r] * DM + c4 * 4);
    }
    __syncthreads();
    const int doV = tid >> 5;        // 0: K path, 1: V path
    const int ep = tid & 31;         // handles e=ep and e=ep+32
    const float* W = doV ? Wv : Wk;
    const float* w0 = W + (size_t)ep * DM;
    const float* w1 = W + (size_t)(ep + 32) * DM;
    float a0[8], a1[8];
#pragma unroll
    for (int r = 0; r < 8; ++r) { a0[r] = 0.f; a1[r] = 0.f; }
    for (int d4 = 0; d4 < DM / 4; ++d4) {
        float4 x0 = *reinterpret_cast<const float4*>(w0 + d4 * 4);
        float4 x1 = *reinterpret_cast<const float4*>(w1 + d4 * 4);
#pragma unroll
        for (int r = 0; r < 8; ++r) {
            float4 m = *reinterpret_cast<const float4*>(&s[doV][r][d4 * 4]);
            a0[r] = fmaf(x0.x, m.x, fmaf(x0.y, m.y, fmaf(x0.z, m.z, fmaf(x0.w, m.w, a0[r]))));
            a1[r] = fmaf(x1.x, m.x, fmaf(x1.y, m.y, fmaf(x1.z, m.z, fmaf(x1.w, m.w, a1[r]))));
        }
    }
    float* O = doV ? Vmem : Kmem;
#pragma unroll
    for (int r = 0; r < 8; ++r) {
        O[(size_t)(i0 + r) * DH_ + ep] = a0[r];
        O[(size_t)(i0 + r) * DH_ + ep + 32] = a1[r];
    }
}

// ---------------------------------------------------------------- k4: W1 partial projections
__global__ __launch_bounds__(128)
void k4_parts(const float* __restrict__ q, const float* __restrict__ kctx,
              const float* __restrict__ Kmem, const float* __restrict__ W1,
              float* __restrict__ qp, float* __restrict__ kcp, float* __restrict__ kmp)
{
    const int bid = blockIdx.x;
    const int tid = threadIdx.x;  // 128 = e
    const float* src; float* dst; int woff;
    if (bid < 1024)      { int r0 = bid * 4;          src = q    + (size_t)r0 * DH_; dst = qp  + (size_t)r0 * HID; woff = 0; }
    else if (bid < 2048) { int r0 = (bid - 1024) * 4; src = kctx + (size_t)r0 * DH_; dst = kcp + (size_t)r0 * HID; woff = DH_; }
    else                 { int r0 = (bid - 2048) * 4; src = Kmem + (size_t)r0 * DH_; dst = kmp + (size_t)r0 * HID; woff = DH_; }
    __shared__ float s[4][DH_];
    for (int l = tid; l < 4 * DH_; l += 128) s[l >> 6][l & 63] = src[l];
    __syncthreads();
    const float* wr = W1 + (size_t)tid * (2 * DH_) + woff;
    float a0 = 0.f, a1 = 0.f, a2 = 0.f, a3 = 0.f;
#pragma unroll 8
    for (int d = 0; d < DH_; ++d) {
        float w = wr[d];
        a0 = fmaf(s[0][d], w, a0);
        a1 = fmaf(s[1][d], w, a1);
        a2 = fmaf(s[2][d], w, a2);
        a3 = fmaf(s[3][d], w, a3);
    }
    dst[0 * HID + tid] = a0;
    dst[1 * HID + tid] = a1;
    dst[2 * HID + tid] = a2;
    dst[3 * HID + tid] = a3;
}

// ---------------------------------------------------------------- k5: MLP scores + softmax + weighted sum
__global__ __launch_bounds__(256)
void k5_attn(const float* __restrict__ qp, const float* __restrict__ kcp,
             const float* __restrict__ kmp, const float* __restrict__ vctx,
             const float* __restrict__ Vmem, const float* __restrict__ b1,
             const float* __restrict__ w2, const float* __restrict__ b2,
             float* __restrict__ out, float* __restrict__ outw)
{
    const int bid = blockIdx.x;
    const int t = bid & 127, h = (bid >> 7) & 7, b = bid >> 10;
    const int tid = threadIdx.x;
    const int lane = tid & 63, wv = tid >> 6;
    const int bh = b * H_ + h, bht = bh * TQ_ + t, bt = b * TQ_ + t;
    constexpr int NS = TK_ + TOPK;  // 160
    __shared__ float qps[HID], b1s[HID], w2s[HID];
    __shared__ float sc[NS];
    __shared__ float red[8];
    if (tid < HID) {
        qps[tid] = qp[(size_t)bht * HID + tid];
        b1s[tid] = b1[tid];
        w2s[tid] = w2[tid];
    }
    __syncthreads();
    const float bias2 = b2[0];
    if (tid < NS) {
        const float* kr = (tid < TK_) ? (kcp + ((size_t)bh * TK_ + tid) * HID)
                                      : (kmp + ((size_t)bt * TOPK + (tid - TK_)) * HID);
        float acc = 0.f;
#pragma unroll 4
        for (int e4 = 0; e4 < HID / 4; ++e4) {
            float4 kv = *reinterpret_cast<const float4*>(kr + e4 * 4);
            acc += fmaxf(qps[e4 * 4 + 0] + kv.x + b1s[e4 * 4 + 0], 0.f) * w2s[e4 * 4 + 0];
            acc += fmaxf(qps[e4 * 4 + 1] + kv.y + b1s[e4 * 4 + 1], 0.f) * w2s[e4 * 4 + 1];
            acc += fmaxf(qps[e4 * 4 + 2] + kv.z + b1s[e4 * 4 + 2], 0.f) * w2s[e4 * 4 + 2];
            acc += fmaxf(qps[e4 * 4 + 3] + kv.w + b1s[e4 * 4 + 3], 0.f) * w2s[e4 * 4 + 3];
        }
        sc[tid] = acc + bias2;
    }
    __syncthreads();
    float v = (tid < NS) ? sc[tid] : -INFINITY;
    float m = v;
#pragma unroll
    for (int off = 1; off < 64; off <<= 1) m = fmaxf(m, __shfl_xor(m, off));
    if (lane == 0) red[wv] = m;
    __syncthreads();
    if (tid == 0) red[4] = fmaxf(fmaxf(red[0], red[1]), fmaxf(red[2], red[3]));
    __syncthreads();
    const float mm = red[4];
    float e = (tid < NS) ? expf(v - mm) : 0.f;
    float ssum = e;
#pragma unroll
    for (int off = 1; off < 64; off <<= 1) ssum += __shfl_xor(ssum, off);
    if (lane == 0) red[wv] = ssum;
    __syncthreads();
    if (tid == 0) red[5] = red[0] + red[1] + red[2] + red[3];
    __syncthreads();
    const float inv = 1.f / red[5];
    if (tid < NS) {
        float w = e * inv;
        sc[tid] = w;
        outw[(size_t)bht * NS + tid] = w;
    }
    __syncthreads();
    if (tid < DH_) {
        float acc = 0.f;
        const float* vb = vctx + (size_t)bh * TK_ * DH_ + tid;
        for (int s2 = 0; s2 < TK_; ++s2) acc = fmaf(sc[s2], vb[(size_t)s2 * DH_], acc);
        const float* vm = Vmem + (size_t)bt * TOPK * DH_ + tid;
#pragma unroll
        for (int kk = 0; kk < TOPK; ++kk) acc = fmaf(sc[TK_ + kk], vm[(size_t)kk * DH_], acc);
        out[(size_t)bht * DH_ + tid] = acc;
    }
}

// ---------------------------------------------------------------- launch
extern "C" void kernel_launch(void* const* d_in, const int* in_sizes, int n_in,
                              void* d_out, int out_size, void* d_ws, size_t ws_size,
                              hipStream_t stream)
{
    const float* q    = (const float*)d_in[0];
    const float* kctx = (const float*)d_in[1];
    const float* vctx = (const float*)d_in[2];
    const float* qm   = (const float*)d_in[3];
    const float* mk   = (const float*)d_in[4];
    const float* mv   = (const float*)d_in[5];
    const float* Wk   = (const float*)d_in[6];
    const float* Wv   = (const float*)d_in[7];
    const float* W1   = (const float*)d_in[8];
    const float* b1   = (const float*)d_in[9];
    const float* w2   = (const float*)d_in[10];
    const float* b2   = (const float*)d_in[11];
    float* out  = (float*)d_out;
    float* outw = out + (size_t)B_ * H_ * TQ_ * DH_;

    char* w = (char*)d_ws;
    unsigned short* mkb = (unsigned short*)w; w += sizeof(unsigned short) * (size_t)NPAD * DM;
    unsigned short* qmb = (unsigned short*)w; w += sizeof(unsigned short) * R_ * DM;
    float* cand_s = (float*)w; w += sizeof(float) * R_ * NCAND;
    int*   cand_i = (int*)w;   w += sizeof(int) * R_ * NCAND;
    int*   sel    = (int*)w;   w += sizeof(int) * R_ * TOPK;
    float* Kmem   = (float*)w; w += sizeof(float) * R_ * TOPK * DH_;
    float* Vmem   = (float*)w; w += sizeof(float) * R_ * TOPK * DH_;
    float* qp     = (float*)w; w += sizeof(float) * B_ * H_ * TQ_ * HID;
    float* kcp    = (float*)w; w += sizeof(float) * B_ * H_ * TK_ * HID;
    float* kmp    = (float*)w; w += sizeof(float) * R_ * TOPK * HID;

    hipLaunchKernelGGL(k0_cvt, dim3(2048), dim3(256), 0, stream,
                       mk, mkb, (long)NMEM * DM, (long)NPAD * DM);
    hipLaunchKernelGGL(k0_cvt, dim3(128), dim3(256), 0, stream,
                       qm, qmb, (long)R_ * DM, (long)R_ * DM);
    hipLaunchKernelGGL(k1_mfma, dim3(8, NCH), dim3(256), 0, stream, qmb, mkb, cand_s, cand_i);
    hipLaunchKernelGGL(k2_select, dim3(R_), dim3(256), 0, stream, qm, mk, cand_s, cand_i, sel);
    hipLaunchKernelGGL(k3_proj, dim3(R_ * TOPK / 8), dim3(64), 0, stream, mk, mv, Wk, Wv, sel, Kmem, Vmem);
    hipLaunchKernelGGL(k4_parts, dim3(6144), dim3(128), 0, stream, q, kctx, Kmem, W1, qp, kcp, kmp);
    hipLaunchKernelGGL(k5_attn, dim3(B_ * H_ * TQ_), dim3(256), 0, stream, qp, kcp, kmp, vctx, Vmem, b1, w2, b2, out, outw);
}

// Round 3
// 447.412 us; speedup vs baseline: 3.0890x; 1.3697x over previous
//
#include <hip/hip_runtime.h>
#include <cmath>

constexpr int B_ = 4, H_ = 8, TQ_ = 128, TK_ = 128, DH_ = 64;
constexpr int NMEM = 100000, DM = 512, TOPK = 32, HID = 128;
constexpr int R_ = B_ * TQ_;                    // 512 memory rows (b,t)
constexpr int CTILE = 128, RTILE = 64;
constexpr int NCH = (NMEM + CTILE - 1) / CTILE; // 782
constexpr int NPAD = NCH * CTILE;               // 100096 padded rows
constexpr int KC = 8;                           // candidates kept per chunk
constexpr int NCAND = NCH * KC;                 // 6256
constexpr int KSEL = 48;                        // min rescored candidates
constexpr int CAP  = 128;                       // max rescored candidates
constexpr int NLD  = (NCAND + 255) / 256;       // 25 keys per thread

using f32x4  = __attribute__((ext_vector_type(4))) float;
using bf16x8 = __attribute__((ext_vector_type(8))) short;
using u16x8  = __attribute__((ext_vector_type(8))) unsigned short;

#define GLOAD16(g, l) __builtin_amdgcn_global_load_lds( \
    (const __attribute__((address_space(1))) void*)(g), \
    (__attribute__((address_space(3))) void*)(l), 16, 0, 0)

static __device__ __forceinline__ unsigned short f2bf(float f) {
    unsigned u = __float_as_uint(f);
    u = (u + 0x7FFFu + ((u >> 16) & 1u)) >> 16;
    return (unsigned short)u;
}

// ---------------------------------------------------------------- k0: fp32 -> bf16 convert (pad rows zeroed)
__global__ __launch_bounds__(256)
void k0_cvt(const float* __restrict__ src, unsigned short* __restrict__ dst,
            long n, long ntot)
{
    long stride = (long)gridDim.x * 256 * 8;
    for (long base = ((long)blockIdx.x * 256 + threadIdx.x) * 8; base < ntot; base += stride) {
        u16x8 o;
        if (base < n) {
            float4 v0 = *reinterpret_cast<const float4*>(src + base);
            float4 v1 = *reinterpret_cast<const float4*>(src + base + 4);
            o[0] = f2bf(v0.x); o[1] = f2bf(v0.y); o[2] = f2bf(v0.z); o[3] = f2bf(v0.w);
            o[4] = f2bf(v1.x); o[5] = f2bf(v1.y); o[6] = f2bf(v1.z); o[7] = f2bf(v1.w);
        } else {
            o = (u16x8)0;
        }
        *reinterpret_cast<u16x8*>(dst + base) = o;
    }
}

// ---------------------------------------------------------------- k1: bf16 MFMA scores + per-chunk top-8
__global__ __launch_bounds__(256)
void k1_mfma(const unsigned short* __restrict__ qmb, const unsigned short* __restrict__ mkb,
             float* __restrict__ cand_s, int* __restrict__ cand_i)
{
    const int rt = blockIdx.x;      // 0..7 row tile (64 rows)
    const int chunk = blockIdx.y;   // 0..781 (128 cols)
    const int row0 = rt * RTILE;
    const int col0 = chunk * CTILE;
    const int tid = threadIdx.x;
    const int lane = tid & 63, w = tid >> 6;
    const int wm = w >> 1, wn = w & 1;          // wave computes 32x64

    // union: tiles A[64][64]bf16 @0 (8 KiB) + B[128][64]bf16 @8192 (16 KiB)  |  sc[64][129] f32 (33024 B)
    __shared__ __align__(16) char smem[64 * 129 * 4];
    char* Abase = smem;
    char* Bbase = smem + 8192;
    float* scf = (float*)smem;

    f32x4 acc[2][4];
#pragma unroll
    for (int mi = 0; mi < 2; ++mi)
#pragma unroll
        for (int ni = 0; ni < 4; ++ni) acc[mi][ni] = (f32x4)0.f;

    for (int ks = 0; ks < 8; ++ks) {
        const int kb = ks * 128;    // byte offset of K-slice within a 1024-B row
        // stage A: 64 rows x 128 B (linear dest, inverse-swizzled source)
#pragma unroll
        for (int p = 0; p < 2; ++p) {
            int X = p * 4096 + w * 1024 + lane * 16;
            int r = X >> 7, c = (X & 127) ^ ((r & 7) << 4);
            const char* src = (const char*)qmb + (size_t)(row0 + r) * 1024 + kb + c;
            GLOAD16(src, Abase + p * 4096 + w * 1024);
        }
        // stage B: 128 rows x 128 B
#pragma unroll
        for (int p = 0; p < 4; ++p) {
            int X = p * 4096 + w * 1024 + lane * 16;
            int r = X >> 7, c = (X & 127) ^ ((r & 7) << 4);
            const char* src = (const char*)mkb + (size_t)(col0 + r) * 1024 + kb + c;
            GLOAD16(src, Bbase + p * 4096 + w * 1024);
        }
        __syncthreads();
#pragma unroll
        for (int kk = 0; kk < 2; ++kk) {
            bf16x8 af[2], bfr[4];
#pragma unroll
            for (int mi = 0; mi < 2; ++mi) {
                int rr = wm * 32 + mi * 16 + (lane & 15);
                int L = rr * 128 + kk * 64 + ((lane >> 4) * 16);
                af[mi] = *reinterpret_cast<const bf16x8*>(Abase + (L ^ ((rr & 7) << 4)));
            }
#pragma unroll
            for (int ni = 0; ni < 4; ++ni) {
                int rr = wn * 64 + ni * 16 + (lane & 15);
                int L = rr * 128 + kk * 64 + ((lane >> 4) * 16);
                bfr[ni] = *reinterpret_cast<const bf16x8*>(Bbase + (L ^ ((rr & 7) << 4)));
            }
#pragma unroll
            for (int mi = 0; mi < 2; ++mi)
#pragma unroll
                for (int ni = 0; ni < 4; ++ni)
                    acc[mi][ni] = __builtin_amdgcn_mfma_f32_16x16x32_bf16(af[mi], bfr[ni], acc[mi][ni], 0, 0, 0);
        }
        __syncthreads();
    }

    // scores -> LDS (C/D layout: col=lane&15, row=(lane>>4)*4+reg), OOB cols masked
#pragma unroll
    for (int mi = 0; mi < 2; ++mi)
#pragma unroll
        for (int ni = 0; ni < 4; ++ni)
#pragma unroll
            for (int reg = 0; reg < 4; ++reg) {
                int rr = wm * 32 + mi * 16 + (lane >> 4) * 4 + reg;
                int cc = wn * 64 + ni * 16 + (lane & 15);
                scf[rr * 129 + cc] = (col0 + cc < NMEM) ? acc[mi][ni][reg] : -INFINITY;
            }
    __syncthreads();

    // per-row top-8, 4 threads per row (intra-wave quad)
    const int rid = tid >> 2, sub = tid & 3;
    float* srow = scf + rid * 129;
    size_t base = (size_t)(row0 + rid) * NCAND + (size_t)chunk * KC;
    for (int it = 0; it < KC; ++it) {
        float best = -INFINITY; int bi = 0;
        for (int c = sub; c < CTILE; c += 4) {
            float v = srow[c];
            if (v > best) { best = v; bi = c; }
        }
#pragma unroll
        for (int off = 1; off < 4; off <<= 1) {
            float ob = __shfl_xor(best, off);
            int   oi = __shfl_xor(bi, off);
            if (ob > best || (ob == best && oi < bi)) { best = ob; bi = oi; }
        }
        if (sub == 0) { cand_s[base + it] = best; cand_i[base + it] = col0 + bi; }
        srow[bi] = -INFINITY;   // all 4 lanes agree on bi
    }
}

// ---------------------------------------------------------------- k2a: threshold select (radix binary search) + gather
__global__ __launch_bounds__(256)
void k2a_thresh(const float* __restrict__ cand_s, const int* __restrict__ cand_i,
                int* __restrict__ cand2_i, int* __restrict__ cand2_n)
{
    const int row = blockIdx.x;
    const int tid = threadIdx.x;
    const int lane = tid & 63, wv = tid >> 6;
    const float* cs = cand_s + (size_t)row * NCAND;

    unsigned key[NLD];
#pragma unroll
    for (int j = 0; j < NLD; ++j) {
        int i = tid + j * 256;
        float v = (i < NCAND) ? cs[i] : -INFINITY;
        unsigned b = __float_as_uint(v);
        key[j] = (b & 0x80000000u) ? ~b : (b | 0x80000000u);
    }

    __shared__ int red[4];
    __shared__ int cnt;
    unsigned lo = 0u;
    int c_cur = NCAND;
    for (int bit = 31; bit >= 0; --bit) {
        if (c_cur <= CAP) break;   // uniform: c_cur identical across block
        unsigned T = lo | (1u << bit);
        int c = 0;
#pragma unroll
        for (int j = 0; j < NLD; ++j) c += (key[j] >= T);
#pragma unroll
        for (int off = 1; off < 64; off <<= 1) c += __shfl_xor(c, off);
        if (lane == 0) red[wv] = c;
        __syncthreads();
        int ct = red[0] + red[1] + red[2] + red[3];
        if (ct >= KSEL) { lo = T; c_cur = ct; }
        __syncthreads();
    }

    if (tid == 0) cnt = 0;
    __syncthreads();
#pragma unroll
    for (int j = 0; j < NLD; ++j) {
        int i = tid + j * 256;
        if (i < NCAND && key[j] >= lo) {
            int p = atomicAdd(&cnt, 1);
            if (p < CAP) cand2_i[(size_t)row * CAP + p] = cand_i[(size_t)row * NCAND + i];
        }
    }
    __syncthreads();
    if (tid == 0) cand2_n[row] = cnt < CAP ? cnt : CAP;
}

// ---------------------------------------------------------------- k2b: fp64 rescore (one wave per candidate)
__global__ __launch_bounds__(256)
void k2b_rescore(const float* __restrict__ qm, const float* __restrict__ mk,
                 const int* __restrict__ cand2_i, const int* __restrict__ cand2_n,
                 double* __restrict__ rsc)
{
    const int row = blockIdx.x;
    const int tid = threadIdx.x;
    const int lane = tid & 63, wv = tid >> 6;
    const int c = blockIdx.y * 4 + wv;
    const int n = cand2_n[row];
    if (c >= n) return;
    const int idx = cand2_i[(size_t)row * CAP + c];
    const float* qrow = qm + (size_t)row * DM;
    const float* krow = mk + (size_t)idx * DM;
    double p = 0.0;
#pragma unroll
    for (int j = 0; j < DM / 64; ++j) {
        int d = lane + j * 64;
        p += (double)qrow[d] * (double)krow[d];
    }
#pragma unroll
    for (int off = 1; off < 64; off <<= 1) p += __shfl_xor(p, off);
    if (lane == 0) rsc[(size_t)row * CAP + c] = p;
}

// ---------------------------------------------------------------- k2c: exact ordered top-32 (one wave per row)
__global__ __launch_bounds__(64)
void k2c_top32(const double* __restrict__ rsc, const int* __restrict__ cand2_i,
               const int* __restrict__ cand2_n, int* __restrict__ sel)
{
    const int row = blockIdx.x;
    const int lane = threadIdx.x;
    const int n = cand2_n[row];
    double v0 = -1.0e300, v1 = -1.0e300;
    int i0 = 0x7fffffff, i1 = 0x7fffffff;
    if (lane < n)      { v0 = rsc[(size_t)row * CAP + lane];      i0 = cand2_i[(size_t)row * CAP + lane]; }
    if (lane + 64 < n) { v1 = rsc[(size_t)row * CAP + lane + 64]; i1 = cand2_i[(size_t)row * CAP + lane + 64]; }
    for (int s = 0; s < TOPK; ++s) {
        double bv; int bi;
        if (v0 > v1 || (v0 == v1 && i0 < i1)) { bv = v0; bi = i0; }
        else                                  { bv = v1; bi = i1; }
#pragma unroll
        for (int off = 1; off < 64; off <<= 1) {
            double ov = __shfl_xor(bv, off);
            int    oi = __shfl_xor(bi, off);
            if (ov > bv || (ov == bv && oi < bi)) { bv = ov; bi = oi; }
        }
        if (lane == 0) sel[row * TOPK + s] = bi;
        if (i0 == bi) v0 = -1.0e300;
        if (i1 == bi) v1 = -1.0e300;
    }
}

// ---------------------------------------------------------------- k3: gather + Wk/Wv projection
__global__ __launch_bounds__(64)
void k3_proj(const float* __restrict__ mk, const float* __restrict__ mv,
             const float* __restrict__ Wk, const float* __restrict__ Wv,
             const int* __restrict__ sel,
             float* __restrict__ Kmem, float* __restrict__ Vmem)
{
    const int i0 = blockIdx.x * 8;   // pair base, pair = row*TOPK+k (16384 total)
    const int tid = threadIdx.x;     // 64
    __shared__ float s[2][8][DM];    // [mat][row][d] 32 KiB
    __shared__ int si[8];
    if (tid < 8) si[tid] = sel[i0 + tid];
    __syncthreads();
    for (int l = tid; l < 1024; l += 64) {   // 8 rows x 128 float4 per matrix
        int r = l >> 7, c4 = l & 127;
        *reinterpret_cast<float4*>(&s[0][r][c4 * 4]) =
            *reinterpret_cast<const float4*>(mk + (size_t)si[r] * DM + c4 * 4);
        *reinterpret_cast<float4*>(&s[1][r][c4 * 4]) =
            *reinterpret_cast<const float4*>(mv + (size_t)si[r] * DM + c4 * 4);
    }
    __syncthreads();
    const int doV = tid >> 5;        // 0: K path, 1: V path
    const int ep = tid & 31;         // handles e=ep and e=ep+32
    const float* W = doV ? Wv : Wk;
    const float* w0 = W + (size_t)ep * DM;
    const float* w1 = W + (size_t)(ep + 32) * DM;
    float a0[8], a1[8];
#pragma unroll
    for (int r = 0; r < 8; ++r) { a0[r] = 0.f; a1[r] = 0.f; }
    for (int d4 = 0; d4 < DM / 4; ++d4) {
        float4 x0 = *reinterpret_cast<const float4*>(w0 + d4 * 4);
        float4 x1 = *reinterpret_cast<const float4*>(w1 + d4 * 4);
#pragma unroll
        for (int r = 0; r < 8; ++r) {
            float4 m = *reinterpret_cast<const float4*>(&s[doV][r][d4 * 4]);
            a0[r] = fmaf(x0.x, m.x, fmaf(x0.y, m.y, fmaf(x0.z, m.z, fmaf(x0.w, m.w, a0[r]))));
            a1[r] = fmaf(x1.x, m.x, fmaf(x1.y, m.y, fmaf(x1.z, m.z, fmaf(x1.w, m.w, a1[r]))));
        }
    }
    float* O = doV ? Vmem : Kmem;
#pragma unroll
    for (int r = 0; r < 8; ++r) {
        O[(size_t)(i0 + r) * DH_ + ep] = a0[r];
        O[(size_t)(i0 + r) * DH_ + ep + 32] = a1[r];
    }
}

// ---------------------------------------------------------------- k4: W1 partial projections
__global__ __launch_bounds__(128)
void k4_parts(const float* __restrict__ q, const float* __restrict__ kctx,
              const float* __restrict__ Kmem, const float* __restrict__ W1,
              float* __restrict__ qp, float* __restrict__ kcp, float* __restrict__ kmp)
{
    const int bid = blockIdx.x;
    const int tid = threadIdx.x;  // 128 = e
    const float* src; float* dst; int woff;
    if (bid < 1024)      { int r0 = bid * 4;          src = q    + (size_t)r0 * DH_; dst = qp  + (size_t)r0 * HID; woff = 0; }
    else if (bid < 2048) { int r0 = (bid - 1024) * 4; src = kctx + (size_t)r0 * DH_; dst = kcp + (size_t)r0 * HID; woff = DH_; }
    else                 { int r0 = (bid - 2048) * 4; src = Kmem + (size_t)r0 * DH_; dst = kmp + (size_t)r0 * HID; woff = DH_; }
    __shared__ float s[4][DH_];
    for (int l = tid; l < 4 * DH_; l += 128) s[l >> 6][l & 63] = src[l];
    __syncthreads();
    const float* wr = W1 + (size_t)tid * (2 * DH_) + woff;
    float a0 = 0.f, a1 = 0.f, a2 = 0.f, a3 = 0.f;
#pragma unroll 8
    for (int d = 0; d < DH_; ++d) {
        float w = wr[d];
        a0 = fmaf(s[0][d], w, a0);
        a1 = fmaf(s[1][d], w, a1);
        a2 = fmaf(s[2][d], w, a2);
        a3 = fmaf(s[3][d], w, a3);
    }
    dst[0 * HID + tid] = a0;
    dst[1 * HID + tid] = a1;
    dst[2 * HID + tid] = a2;
    dst[3 * HID + tid] = a3;
}

// ---------------------------------------------------------------- k5: MLP scores + softmax + weighted sum
__global__ __launch_bounds__(256)
void k5_attn(const float* __restrict__ qp, const float* __restrict__ kcp,
             const float* __restrict__ kmp, const float* __restrict__ vctx,
             const float* __restrict__ Vmem, const float* __restrict__ b1,
             const float* __restrict__ w2, const float* __restrict__ b2,
             float* __restrict__ out, float* __restrict__ outw)
{
    const int bid = blockIdx.x;
    const int t = bid & 127, h = (bid >> 7) & 7, b = bid >> 10;
    const int tid = threadIdx.x;
    const int lane = tid & 63, wv = tid >> 6;
    const int bh = b * H_ + h, bht = bh * TQ_ + t, bt = b * TQ_ + t;
    constexpr int NS = TK_ + TOPK;  // 160
    __shared__ float qps[HID], b1s[HID], w2s[HID];
    __shared__ float sc[NS];
    __shared__ float red[8];
    if (tid < HID) {
        qps[tid] = qp[(size_t)bht * HID + tid];
        b1s[tid] = b1[tid];
        w2s[tid] = w2[tid];
    }
    __syncthreads();
    const float bias2 = b2[0];
    if (tid < NS) {
        const float* kr = (tid < TK_) ? (kcp + ((size_t)bh * TK_ + tid) * HID)
                                      : (kmp + ((size_t)bt * TOPK + (tid - TK_)) * HID);
        float acc = 0.f;
#pragma unroll 4
        for (int e4 = 0; e4 < HID / 4; ++e4) {
            float4 kv = *reinterpret_cast<const float4*>(kr + e4 * 4);
            acc += fmaxf(qps[e4 * 4 + 0] + kv.x + b1s[e4 * 4 + 0], 0.f) * w2s[e4 * 4 + 0];
            acc += fmaxf(qps[e4 * 4 + 1] + kv.y + b1s[e4 * 4 + 1], 0.f) * w2s[e4 * 4 + 1];
            acc += fmaxf(qps[e4 * 4 + 2] + kv.z + b1s[e4 * 4 + 2], 0.f) * w2s[e4 * 4 + 2];
            acc += fmaxf(qps[e4 * 4 + 3] + kv.w + b1s[e4 * 4 + 3], 0.f) * w2s[e4 * 4 + 3];
        }
        sc[tid] = acc + bias2;
    }
    __syncthreads();
    float v = (tid < NS) ? sc[tid] : -INFINITY;
    float m = v;
#pragma unroll
    for (int off = 1; off < 64; off <<= 1) m = fmaxf(m, __shfl_xor(m, off));
    if (lane == 0) red[wv] = m;
    __syncthreads();
    if (tid == 0) red[4] = fmaxf(fmaxf(red[0], red[1]), fmaxf(red[2], red[3]));
    __syncthreads();
    const float mm = red[4];
    float e = (tid < NS) ? expf(v - mm) : 0.f;
    float ssum = e;
#pragma unroll
    for (int off = 1; off < 64; off <<= 1) ssum += __shfl_xor(ssum, off);
    if (lane == 0) red[wv] = ssum;
    __syncthreads();
    if (tid == 0) red[5] = red[0] + red[1] + red[2] + red[3];
    __syncthreads();
    const float inv = 1.f / red[5];
    if (tid < NS) {
        float w = e * inv;
        sc[tid] = w;
        outw[(size_t)bht * NS + tid] = w;
    }
    __syncthreads();
    if (tid < DH_) {
        float acc = 0.f;
        const float* vb = vctx + (size_t)bh * TK_ * DH_ + tid;
        for (int s2 = 0; s2 < TK_; ++s2) acc = fmaf(sc[s2], vb[(size_t)s2 * DH_], acc);
        const float* vm = Vmem + (size_t)bt * TOPK * DH_ + tid;
#pragma unroll
        for (int kk = 0; kk < TOPK; ++kk) acc = fmaf(sc[TK_ + kk], vm[(size_t)kk * DH_], acc);
        out[(size_t)bht * DH_ + tid] = acc;
    }
}

// ---------------------------------------------------------------- launch
extern "C" void kernel_launch(void* const* d_in, const int* in_sizes, int n_in,
                              void* d_out, int out_size, void* d_ws, size_t ws_size,
                              hipStream_t stream)
{
    const float* q    = (const float*)d_in[0];
    const float* kctx = (const float*)d_in[1];
    const float* vctx = (const float*)d_in[2];
    const float* qm   = (const float*)d_in[3];
    const float* mk   = (const float*)d_in[4];
    const float* mv   = (const float*)d_in[5];
    const float* Wk   = (const float*)d_in[6];
    const float* Wv   = (const float*)d_in[7];
    const float* W1   = (const float*)d_in[8];
    const float* b1   = (const float*)d_in[9];
    const float* w2   = (const float*)d_in[10];
    const float* b2   = (const float*)d_in[11];
    float* out  = (float*)d_out;
    float* outw = out + (size_t)B_ * H_ * TQ_ * DH_;

    char* w = (char*)d_ws;
    unsigned short* mkb = (unsigned short*)w; w += sizeof(unsigned short) * (size_t)NPAD * DM;
    unsigned short* qmb = (unsigned short*)w; w += sizeof(unsigned short) * R_ * DM;
    float* cand_s = (float*)w; w += sizeof(float) * R_ * NCAND;
    int*   cand_i = (int*)w;   w += sizeof(int) * R_ * NCAND;
    int*   cand2_i= (int*)w;   w += sizeof(int) * R_ * CAP;
    int*   cand2_n= (int*)w;   w += sizeof(int) * R_;
    double* rsc   = (double*)w; w += sizeof(double) * R_ * CAP;
    int*   sel    = (int*)w;   w += sizeof(int) * R_ * TOPK;
    float* Kmem   = (float*)w; w += sizeof(float) * R_ * TOPK * DH_;
    float* Vmem   = (float*)w; w += sizeof(float) * R_ * TOPK * DH_;
    float* qp     = (float*)w; w += sizeof(float) * B_ * H_ * TQ_ * HID;
    float* kcp    = (float*)w; w += sizeof(float) * B_ * H_ * TK_ * HID;
    float* kmp    = (float*)w; w += sizeof(float) * R_ * TOPK * HID;

    hipLaunchKernelGGL(k0_cvt, dim3(2048), dim3(256), 0, stream,
                       mk, mkb, (long)NMEM * DM, (long)NPAD * DM);
    hipLaunchKernelGGL(k0_cvt, dim3(128), dim3(256), 0, stream,
                       qm, qmb, (long)R_ * DM, (long)R_ * DM);
    hipLaunchKernelGGL(k1_mfma, dim3(8, NCH), dim3(256), 0, stream, qmb, mkb, cand_s, cand_i);
    hipLaunchKernelGGL(k2a_thresh, dim3(R_), dim3(256), 0, stream, cand_s, cand_i, cand2_i, cand2_n);
    hipLaunchKernelGGL(k2b_rescore, dim3(R_, CAP / 4), dim3(256), 0, stream, qm, mk, cand2_i, cand2_n, rsc);
    hipLaunchKernelGGL(k2c_top32, dim3(R_), dim3(64), 0, stream, rsc, cand2_i, cand2_n, sel);
    hipLaunchKernelGGL(k3_proj, dim3(R_ * TOPK / 8), dim3(64), 0, stream, mk, mv, Wk, Wv, sel, Kmem, Vmem);
    hipLaunchKernelGGL(k4_parts, dim3(6144), dim3(128), 0, stream, q, kctx, Kmem, W1, qp, kcp, kmp);
    hipLaunchKernelGGL(k5_attn, dim3(B_ * H_ * TQ_), dim3(256), 0, stream, qp, kcp, kmp, vctx, Vmem, b1, w2, b2, out, outw);
}

// Round 4
// 361.013 us; speedup vs baseline: 3.8283x; 1.2393x over previous
//
#include <hip/hip_runtime.h>
#include <cmath>

constexpr int B_ = 4, H_ = 8, TQ_ = 128, TK_ = 128, DH_ = 64;
constexpr int NMEM = 100000, DM = 512, TOPK = 32, HID = 128;
constexpr int R_ = B_ * TQ_;                    // 512 memory rows (b,t)
constexpr int CTILE = 128, RTILE = 64;
constexpr int NCHP = 784;                       // padded chunk count (8 XCDs x 98)
constexpr int NPAD = NCHP * CTILE;              // 100352 padded rows
constexpr int KC = 16;                          // candidates kept per chunk (4 per thread-slice)
constexpr int NCAND = NCHP * KC;                // 12544 = 49*256
constexpr int KSEL = 48;                        // min rescored candidates
constexpr int CAP  = 128;                       // max rescored candidates
constexpr int NLD  = NCAND / 256;               // 49 keys per thread (exact)

using f32x4  = __attribute__((ext_vector_type(4))) float;
using bf16x8 = __attribute__((ext_vector_type(8))) short;
using u16x8  = __attribute__((ext_vector_type(8))) unsigned short;

#define GLOAD16(g, l) __builtin_amdgcn_global_load_lds( \
    (const __attribute__((address_space(1))) void*)(g), \
    (__attribute__((address_space(3))) void*)(l), 16, 0, 0)

static __device__ __forceinline__ unsigned short f2bf(float f) {
    unsigned u = __float_as_uint(f);
    u = (u + 0x7FFFu + ((u >> 16) & 1u)) >> 16;
    return (unsigned short)u;
}

// ---------------------------------------------------------------- k0: fp32 -> bf16 convert (pad rows zeroed)
__global__ __launch_bounds__(256)
void k0_cvt(const float* __restrict__ src, unsigned short* __restrict__ dst,
            long n, long ntot)
{
    long stride = (long)gridDim.x * 256 * 8;
    for (long base = ((long)blockIdx.x * 256 + threadIdx.x) * 8; base < ntot; base += stride) {
        u16x8 o;
        if (base < n) {
            float4 v0 = *reinterpret_cast<const float4*>(src + base);
            float4 v1 = *reinterpret_cast<const float4*>(src + base + 4);
            o[0] = f2bf(v0.x); o[1] = f2bf(v0.y); o[2] = f2bf(v0.z); o[3] = f2bf(v0.w);
            o[4] = f2bf(v1.x); o[5] = f2bf(v1.y); o[6] = f2bf(v1.z); o[7] = f2bf(v1.w);
        } else {
            o = (u16x8)0;
        }
        *reinterpret_cast<u16x8*>(dst + base) = o;
    }
}

// ---------------------------------------------------------------- k1: bf16 MFMA scores + per-chunk top-16
__global__ __launch_bounds__(256)
void k1_mfma(const unsigned short* __restrict__ qmb, const unsigned short* __restrict__ mkb,
             unsigned* __restrict__ cand_k, int* __restrict__ cand_i)
{
    // XCD-aware decomposition: blocks sharing a chunk land on the SAME XCD,
    // consecutively, so the B tile is fetched into that XCD's L2 exactly once.
    const int wgid = blockIdx.x;          // 0..6271
    const int xcd = wgid & 7;
    const int k9 = wgid >> 3;             // 0..783
    const int chunk = xcd * 98 + (k9 >> 3);
    const int rt = k9 & 7;
    const int row0 = rt * RTILE;
    const int col0 = chunk * CTILE;
    const int tid = threadIdx.x;
    const int lane = tid & 63, w = tid >> 6;
    const int wm = w >> 1, wn = w & 1;    // wave computes 32x64

    // union: A[64][64]bf16 @0 (8 KiB) + B[128][64]bf16 @8192 (16 KiB)  |  sc[64][132] f32 (33792 B)
    __shared__ __align__(16) char smem[64 * 132 * 4];
    char* Abase = smem;
    char* Bbase = smem + 8192;
    float* scf = (float*)smem;

    // hoisted staging source pointers (swizzled source, linear LDS dest)
    const char* srcA[2];
    const char* srcB[4];
#pragma unroll
    for (int p = 0; p < 2; ++p) {
        int X = p * 4096 + w * 1024 + lane * 16;
        int r = X >> 7, c = (X & 127) ^ ((r & 7) << 4);
        srcA[p] = (const char*)qmb + (size_t)(row0 + r) * 1024 + c;
    }
#pragma unroll
    for (int p = 0; p < 4; ++p) {
        int X = p * 4096 + w * 1024 + lane * 16;
        int r = X >> 7, c = (X & 127) ^ ((r & 7) << 4);
        srcB[p] = (const char*)mkb + (size_t)(col0 + r) * 1024 + c;
    }
    // hoisted LDS fragment byte-offsets
    int aoff[2][2], boff[4][2];
#pragma unroll
    for (int mi = 0; mi < 2; ++mi) {
        int rr = wm * 32 + mi * 16 + (lane & 15);
        int bse = rr * 128 + ((lane >> 4) * 16);
        aoff[mi][0] = bse ^ ((rr & 7) << 4);
        aoff[mi][1] = (bse + 64) ^ ((rr & 7) << 4);
    }
#pragma unroll
    for (int ni = 0; ni < 4; ++ni) {
        int rr = wn * 64 + ni * 16 + (lane & 15);
        int bse = rr * 128 + ((lane >> 4) * 16);
        boff[ni][0] = 8192 + (bse ^ ((rr & 7) << 4));
        boff[ni][1] = 8192 + ((bse + 64) ^ ((rr & 7) << 4));
    }

    f32x4 acc[2][4];
#pragma unroll
    for (int mi = 0; mi < 2; ++mi)
#pragma unroll
        for (int ni = 0; ni < 4; ++ni) acc[mi][ni] = (f32x4)0.f;

    for (int ks = 0; ks < 8; ++ks) {
#pragma unroll
        for (int p = 0; p < 2; ++p) {
            GLOAD16(srcA[p], Abase + p * 4096 + w * 1024);
            srcA[p] += 128;
        }
#pragma unroll
        for (int p = 0; p < 4; ++p) {
            GLOAD16(srcB[p], Bbase + p * 4096 + w * 1024);
            srcB[p] += 128;
        }
        __syncthreads();
#pragma unroll
        for (int kk = 0; kk < 2; ++kk) {
            bf16x8 af[2], bfr[4];
#pragma unroll
            for (int mi = 0; mi < 2; ++mi)
                af[mi] = *reinterpret_cast<const bf16x8*>(smem + aoff[mi][kk]);
#pragma unroll
            for (int ni = 0; ni < 4; ++ni)
                bfr[ni] = *reinterpret_cast<const bf16x8*>(smem + boff[ni][kk]);
#pragma unroll
            for (int mi = 0; mi < 2; ++mi)
#pragma unroll
                for (int ni = 0; ni < 4; ++ni)
                    acc[mi][ni] = __builtin_amdgcn_mfma_f32_16x16x32_bf16(af[mi], bfr[ni], acc[mi][ni], 0, 0, 0);
        }
        __syncthreads();
    }

    // scores -> LDS (C/D layout: col=lane&15, row=(lane>>4)*4+reg), OOB cols masked; stride 132
#pragma unroll
    for (int mi = 0; mi < 2; ++mi)
#pragma unroll
        for (int ni = 0; ni < 4; ++ni)
#pragma unroll
            for (int reg = 0; reg < 4; ++reg) {
                int rr = wm * 32 + mi * 16 + (lane >> 4) * 4 + reg;
                int cc = wn * 64 + ni * 16 + (lane & 15);
                scf[rr * 132 + cc] = (col0 + cc < NMEM) ? acc[mi][ni][reg] : -INFINITY;
            }
    __syncthreads();

    // single-pass per-thread top-4 over a strided 32-element slice (4 threads per row)
    const int rid = tid >> 2, sub = tid & 3;
    const float* srow = scf + rid * 132;
    unsigned long long t0 = 0ull, t1 = 0ull, t2 = 0ull, t3 = 0ull;
#pragma unroll 8
    for (int i = 0; i < 32; ++i) {
        int c = sub + 4 * i;
        float v = srow[c];
        unsigned b = __float_as_uint(v);
        unsigned s = b ^ ((unsigned)((int)b >> 31) | 0x80000000u);   // order-preserving key
        unsigned long long k = ((unsigned long long)s << 7) | (unsigned)(127 - c);
        bool g0 = k > t0, g1 = k > t1, g2 = k > t2, g3 = k > t3;
        unsigned long long n0 = g0 ? k : t0;
        unsigned long long n1 = g0 ? t0 : (g1 ? k : t1);
        unsigned long long n2 = g1 ? t1 : (g2 ? k : t2);
        unsigned long long n3 = g2 ? t2 : (g3 ? k : t3);
        t0 = n0; t1 = n1; t2 = n2; t3 = n3;
    }
    size_t base = (size_t)(row0 + rid) * NCAND + (size_t)chunk * KC + sub * 4;
    uint4 kv, iv;
    kv.x = (unsigned)(t0 >> 7); iv.x = col0 + 127 - (int)(t0 & 127u);
    kv.y = (unsigned)(t1 >> 7); iv.y = col0 + 127 - (int)(t1 & 127u);
    kv.z = (unsigned)(t2 >> 7); iv.z = col0 + 127 - (int)(t2 & 127u);
    kv.w = (unsigned)(t3 >> 7); iv.w = col0 + 127 - (int)(t3 & 127u);
    *reinterpret_cast<uint4*>(cand_k + base) = kv;
    *reinterpret_cast<uint4*>(cand_i + base) = iv;
}

// ---------------------------------------------------------------- k2a: threshold select (radix binary search) + gather
__global__ __launch_bounds__(256)
void k2a_thresh(const unsigned* __restrict__ cand_k, const int* __restrict__ cand_i,
                int* __restrict__ cand2_i, int* __restrict__ cand2_n)
{
    const int row = blockIdx.x;
    const int tid = threadIdx.x;
    const int lane = tid & 63, wv = tid >> 6;
    const unsigned* ck = cand_k + (size_t)row * NCAND;

    unsigned key[NLD];
#pragma unroll
    for (int j = 0; j < NLD; ++j) key[j] = ck[tid + j * 256];

    __shared__ int red[4];
    __shared__ int cnt;
    unsigned lo = 0u;
    int c_cur = NCAND;
    for (int bit = 31; bit >= 0; --bit) {
        if (c_cur <= CAP) break;   // uniform across block
        unsigned T = lo | (1u << bit);
        int c = 0;
#pragma unroll
        for (int j = 0; j < NLD; ++j) c += (key[j] >= T);
#pragma unroll
        for (int off = 1; off < 64; off <<= 1) c += __shfl_xor(c, off);
        if (lane == 0) red[wv] = c;
        __syncthreads();
        int ct = red[0] + red[1] + red[2] + red[3];
        if (ct >= KSEL) { lo = T; c_cur = ct; }
        __syncthreads();
    }

    if (tid == 0) cnt = 0;
    __syncthreads();
#pragma unroll
    for (int j = 0; j < NLD; ++j) {
        if (key[j] >= lo) {
            int p = atomicAdd(&cnt, 1);
            if (p < CAP) cand2_i[(size_t)row * CAP + p] = cand_i[(size_t)row * NCAND + tid + j * 256];
        }
    }
    __syncthreads();
    if (tid == 0) cand2_n[row] = cnt < CAP ? cnt : CAP;
}

// ---------------------------------------------------------------- k2b: fp64 rescore (one wave per candidate)
__global__ __launch_bounds__(256)
void k2b_rescore(const float* __restrict__ qm, const float* __restrict__ mk,
                 const int* __restrict__ cand2_i, const int* __restrict__ cand2_n,
                 double* __restrict__ rsc)
{
    const int row = blockIdx.x;
    const int tid = threadIdx.x;
    const int lane = tid & 63, wv = tid >> 6;
    const int c = blockIdx.y * 4 + wv;
    const int n = cand2_n[row];
    if (c >= n) return;
    const int idx = cand2_i[(size_t)row * CAP + c];
    const float* qrow = qm + (size_t)row * DM;
    const float* krow = mk + (size_t)idx * DM;
    double p = 0.0;
#pragma unroll
    for (int j = 0; j < DM / 64; ++j) {
        int d = lane + j * 64;
        p += (double)qrow[d] * (double)krow[d];
    }
#pragma unroll
    for (int off = 1; off < 64; off <<= 1) p += __shfl_xor(p, off);
    if (lane == 0) rsc[(size_t)row * CAP + c] = p;
}

// ---------------------------------------------------------------- k2c: exact ordered top-32 (one wave per row)
__global__ __launch_bounds__(64)
void k2c_top32(const double* __restrict__ rsc, const int* __restrict__ cand2_i,
               const int* __restrict__ cand2_n, int* __restrict__ sel)
{
    const int row = blockIdx.x;
    const int lane = threadIdx.x;
    const int n = cand2_n[row];
    double v0 = -1.0e300, v1 = -1.0e300;
    int i0 = 0x7fffffff, i1 = 0x7fffffff;
    if (lane < n)      { v0 = rsc[(size_t)row * CAP + lane];      i0 = cand2_i[(size_t)row * CAP + lane]; }
    if (lane + 64 < n) { v1 = rsc[(size_t)row * CAP + lane + 64]; i1 = cand2_i[(size_t)row * CAP + lane + 64]; }
    for (int s = 0; s < TOPK; ++s) {
        double bv; int bi;
        if (v0 > v1 || (v0 == v1 && i0 < i1)) { bv = v0; bi = i0; }
        else                                  { bv = v1; bi = i1; }
#pragma unroll
        for (int off = 1; off < 64; off <<= 1) {
            double ov = __shfl_xor(bv, off);
            int    oi = __shfl_xor(bi, off);
            if (ov > bv || (ov == bv && oi < bi)) { bv = ov; bi = oi; }
        }
        if (lane == 0) sel[row * TOPK + s] = bi;
        if (i0 == bi) v0 = -1.0e300;
        if (i1 == bi) v1 = -1.0e300;
    }
}

// ---------------------------------------------------------------- k3: gather + Wk/Wv projection
__global__ __launch_bounds__(64)
void k3_proj(const float* __restrict__ mk, const float* __restrict__ mv,
             const float* __restrict__ Wk, const float* __restrict__ Wv,
             const int* __restrict__ sel,
             float* __restrict__ Kmem, float* __restrict__ Vmem)
{
    const int i0 = blockIdx.x * 8;   // pair base, pair = row*TOPK+k (16384 total)
    const int tid = threadIdx.x;     // 64
    __shared__ float s[2][8][DM];    // [mat][row][d] 32 KiB
    __shared__ int si[8];
    if (tid < 8) si[tid] = sel[i0 + tid];
    __syncthreads();
    for (int l = tid; l < 1024; l += 64) {   // 8 rows x 128 float4 per matrix
        int r = l >> 7, c4 = l & 127;
        *reinterpret_cast<float4*>(&s[0][r][c4 * 4]) =
            *reinterpret_cast<const float4*>(mk + (size_t)si[r] * DM + c4 * 4);
        *reinterpret_cast<float4*>(&s[1][r][c4 * 4]) =
            *reinterpret_cast<const float4*>(mv + (size_t)si[r] * DM + c4 * 4);
    }
    __syncthreads();
    const int doV = tid >> 5;        // 0: K path, 1: V path
    const int ep = tid & 31;         // handles e=ep and e=ep+32
    const float* W = doV ? Wv : Wk;
    const float* w0 = W + (size_t)ep * DM;
    const float* w1 = W + (size_t)(ep + 32) * DM;
    float a0[8], a1[8];
#pragma unroll
    for (int r = 0; r < 8; ++r) { a0[r] = 0.f; a1[r] = 0.f; }
    for (int d4 = 0; d4 < DM / 4; ++d4) {
        float4 x0 = *reinterpret_cast<const float4*>(w0 + d4 * 4);
        float4 x1 = *reinterpret_cast<const float4*>(w1 + d4 * 4);
#pragma unroll
        for (int r = 0; r < 8; ++r) {
            float4 m = *reinterpret_cast<const float4*>(&s[doV][r][d4 * 4]);
            a0[r] = fmaf(x0.x, m.x, fmaf(x0.y, m.y, fmaf(x0.z, m.z, fmaf(x0.w, m.w, a0[r]))));
            a1[r] = fmaf(x1.x, m.x, fmaf(x1.y, m.y, fmaf(x1.z, m.z, fmaf(x1.w, m.w, a1[r]))));
        }
    }
    float* O = doV ? Vmem : Kmem;
#pragma unroll
    for (int r = 0; r < 8; ++r) {
        O[(size_t)(i0 + r) * DH_ + ep] = a0[r];
        O[(size_t)(i0 + r) * DH_ + ep + 32] = a1[r];
    }
}

// ---------------------------------------------------------------- k4: W1 partial projections
__global__ __launch_bounds__(128)
void k4_parts(const float* __restrict__ q, const float* __restrict__ kctx,
              const float* __restrict__ Kmem, const float* __restrict__ W1,
              float* __restrict__ qp, float* __restrict__ kcp, float* __restrict__ kmp)
{
    const int bid = blockIdx.x;
    const int tid = threadIdx.x;  // 128 = e
    const float* src; float* dst; int woff;
    if (bid < 1024)      { int r0 = bid * 4;          src = q    + (size_t)r0 * DH_; dst = qp  + (size_t)r0 * HID; woff = 0; }
    else if (bid < 2048) { int r0 = (bid - 1024) * 4; src = kctx + (size_t)r0 * DH_; dst = kcp + (size_t)r0 * HID; woff = DH_; }
    else                 { int r0 = (bid - 2048) * 4; src = Kmem + (size_t)r0 * DH_; dst = kmp + (size_t)r0 * HID; woff = DH_; }
    __shared__ float s[4][DH_];
    for (int l = tid; l < 4 * DH_; l += 128) s[l >> 6][l & 63] = src[l];
    __syncthreads();
    const float* wr = W1 + (size_t)tid * (2 * DH_) + woff;
    float a0 = 0.f, a1 = 0.f, a2 = 0.f, a3 = 0.f;
#pragma unroll 8
    for (int d = 0; d < DH_; ++d) {
        float w = wr[d];
        a0 = fmaf(s[0][d], w, a0);
        a1 = fmaf(s[1][d], w, a1);
        a2 = fmaf(s[2][d], w, a2);
        a3 = fmaf(s[3][d], w, a3);
    }
    dst[0 * HID + tid] = a0;
    dst[1 * HID + tid] = a1;
    dst[2 * HID + tid] = a2;
    dst[3 * HID + tid] = a3;
}

// ---------------------------------------------------------------- k5: MLP scores + softmax + weighted sum
__global__ __launch_bounds__(256)
void k5_attn(const float* __restrict__ qp, const float* __restrict__ kcp,
             const float* __restrict__ kmp, const float* __restrict__ vctx,
             const float* __restrict__ Vmem, const float* __restrict__ b1,
             const float* __restrict__ w2, const float* __restrict__ b2,
             float* __restrict__ out, float* __restrict__ outw)
{
    const int bid = blockIdx.x;
    const int t = bid & 127, h = (bid >> 7) & 7, b = bid >> 10;
    const int tid = threadIdx.x;
    const int lane = tid & 63, wv = tid >> 6;
    const int bh = b * H_ + h, bht = bh * TQ_ + t, bt = b * TQ_ + t;
    constexpr int NS = TK_ + TOPK;  // 160
    __shared__ float qps[HID], b1s[HID], w2s[HID];
    __shared__ float sc[NS];
    __shared__ float red[8];
    if (tid < HID) {
        qps[tid] = qp[(size_t)bht * HID + tid];
        b1s[tid] = b1[tid];
        w2s[tid] = w2[tid];
    }
    __syncthreads();
    const float bias2 = b2[0];
    if (tid < NS) {
        const float* kr = (tid < TK_) ? (kcp + ((size_t)bh * TK_ + tid) * HID)
                                      : (kmp + ((size_t)bt * TOPK + (tid - TK_)) * HID);
        float acc = 0.f;
#pragma unroll 4
        for (int e4 = 0; e4 < HID / 4; ++e4) {
            float4 kv = *reinterpret_cast<const float4*>(kr + e4 * 4);
            acc += fmaxf(qps[e4 * 4 + 0] + kv.x + b1s[e4 * 4 + 0], 0.f) * w2s[e4 * 4 + 0];
            acc += fmaxf(qps[e4 * 4 + 1] + kv.y + b1s[e4 * 4 + 1], 0.f) * w2s[e4 * 4 + 1];
            acc += fmaxf(qps[e4 * 4 + 2] + kv.z + b1s[e4 * 4 + 2], 0.f) * w2s[e4 * 4 + 2];
            acc += fmaxf(qps[e4 * 4 + 3] + kv.w + b1s[e4 * 4 + 3], 0.f) * w2s[e4 * 4 + 3];
        }
        sc[tid] = acc + bias2;
    }
    __syncthreads();
    float v = (tid < NS) ? sc[tid] : -INFINITY;
    float m = v;
#pragma unroll
    for (int off = 1; off < 64; off <<= 1) m = fmaxf(m, __shfl_xor(m, off));
    if (lane == 0) red[wv] = m;
    __syncthreads();
    if (tid == 0) red[4] = fmaxf(fmaxf(red[0], red[1]), fmaxf(red[2], red[3]));
    __syncthreads();
    const float mm = red[4];
    float e = (tid < NS) ? expf(v - mm) : 0.f;
    float ssum = e;
#pragma unroll
    for (int off = 1; off < 64; off <<= 1) ssum += __shfl_xor(ssum, off);
    if (lane == 0) red[wv] = ssum;
    __syncthreads();
    if (tid == 0) red[5] = red[0] + red[1] + red[2] + red[3];
    __syncthreads();
    const float inv = 1.f / red[5];
    if (tid < NS) {
        float w = e * inv;
        sc[tid] = w;
        outw[(size_t)bht * NS + tid] = w;
    }
    __syncthreads();
    if (tid < DH_) {
        float acc = 0.f;
        const float* vb = vctx + (size_t)bh * TK_ * DH_ + tid;
        for (int s2 = 0; s2 < TK_; ++s2) acc = fmaf(sc[s2], vb[(size_t)s2 * DH_], acc);
        const float* vm = Vmem + (size_t)bt * TOPK * DH_ + tid;
#pragma unroll
        for (int kk = 0; kk < TOPK; ++kk) acc = fmaf(sc[TK_ + kk], vm[(size_t)kk * DH_], acc);
        out[(size_t)bht * DH_ + tid] = acc;
    }
}

// ---------------------------------------------------------------- launch
extern "C" void kernel_launch(void* const* d_in, const int* in_sizes, int n_in,
                              void* d_out, int out_size, void* d_ws, size_t ws_size,
                              hipStream_t stream)
{
    const float* q    = (const float*)d_in[0];
    const float* kctx = (const float*)d_in[1];
    const float* vctx = (const float*)d_in[2];
    const float* qm   = (const float*)d_in[3];
    const float* mk   = (const float*)d_in[4];
    const float* mv   = (const float*)d_in[5];
    const float* Wk   = (const float*)d_in[6];
    const float* Wv   = (const float*)d_in[7];
    const float* W1   = (const float*)d_in[8];
    const float* b1   = (const float*)d_in[9];
    const float* w2   = (const float*)d_in[10];
    const float* b2   = (const float*)d_in[11];
    float* out  = (float*)d_out;
    float* outw = out + (size_t)B_ * H_ * TQ_ * DH_;

    char* w = (char*)d_ws;
    unsigned short* mkb = (unsigned short*)w; w += sizeof(unsigned short) * (size_t)NPAD * DM;
    unsigned short* qmb = (unsigned short*)w; w += sizeof(unsigned short) * R_ * DM;
    unsigned* cand_k = (unsigned*)w; w += sizeof(unsigned) * (size_t)R_ * NCAND;
    int*   cand_i = (int*)w;   w += sizeof(int) * (size_t)R_ * NCAND;
    int*   cand2_i= (int*)w;   w += sizeof(int) * R_ * CAP;
    int*   cand2_n= (int*)w;   w += sizeof(int) * R_;
    double* rsc   = (double*)w; w += sizeof(double) * R_ * CAP;
    int*   sel    = (int*)w;   w += sizeof(int) * R_ * TOPK;
    float* Kmem   = (float*)w; w += sizeof(float) * R_ * TOPK * DH_;
    float* Vmem   = (float*)w; w += sizeof(float) * R_ * TOPK * DH_;
    float* qp     = (float*)w; w += sizeof(float) * B_ * H_ * TQ_ * HID;
    float* kcp    = (float*)w; w += sizeof(float) * B_ * H_ * TK_ * HID;
    float* kmp    = (float*)w; w += sizeof(float) * R_ * TOPK * HID;

    hipLaunchKernelGGL(k0_cvt, dim3(2048), dim3(256), 0, stream,
                       mk, mkb, (long)NMEM * DM, (long)NPAD * DM);
    hipLaunchKernelGGL(k0_cvt, dim3(128), dim3(256), 0, stream,
                       qm, qmb, (long)R_ * DM, (long)R_ * DM);
    hipLaunchKernelGGL(k1_mfma, dim3(NCHP * 8), dim3(256), 0, stream, qmb, mkb, cand_k, cand_i);
    hipLaunchKernelGGL(k2a_thresh, dim3(R_), dim3(256), 0, stream, cand_k, cand_i, cand2_i, cand2_n);
    hipLaunchKernelGGL(k2b_rescore, dim3(R_, CAP / 4), dim3(256), 0, stream, qm, mk, cand2_i, cand2_n, rsc);
    hipLaunchKernelGGL(k2c_top32, dim3(R_), dim3(64), 0, stream, rsc, cand2_i, cand2_n, sel);
    hipLaunchKernelGGL(k3_proj, dim3(R_ * TOPK / 8), dim3(64), 0, stream, mk, mv, Wk, Wv, sel, Kmem, Vmem);
    hipLaunchKernelGGL(k4_parts, dim3(6144), dim3(128), 0, stream, q, kctx, Kmem, W1, qp, kcp, kmp);
    hipLaunchKernelGGL(k5_attn, dim3(B_ * H_ * TQ_), dim3(256), 0, stream, qp, kcp, kmp, vctx, Vmem, b1, w2, b2, out, outw);
}